// Round 2
// baseline (226.505 us; speedup 1.0000x reference)
//
#include <hip/hip_runtime.h>
#include <hip/hip_bf16.h>
#include <cmath>

#define D 256
#define NH 8
#define B 2
#define EPW 8      // edges per wave (bf16 path) -- m=320000 divides exactly
#define EPW32 4    // edges per wave (f32 fallback path)

__device__ inline unsigned short f2bf(float f) {
    unsigned u = __float_as_uint(f);
    unsigned r = u + 0x7FFFu + ((u >> 16) & 1u);   // RNE
    return (unsigned short)(r >> 16);
}

// K0: fp32 [bb][node][d] -> packed bf16 [node][bb][d] (1KB per node covers
// both batches). One thread = 8 floats -> one 16B uint4 store.
__global__ __launch_bounds__(256) void k_conv(
    const float* __restrict__ q, const float* __restrict__ k,
    uint4* __restrict__ qc, uint4* __restrict__ kc, int n)
{
    int total = n * B * 32;   // 32 8-float chunks per (bb,node) row
    for (int i = blockIdx.x * blockDim.x + threadIdx.x; i < total;
         i += gridDim.x * blockDim.x) {
        int c   = i & 31;                 // chunk within row
        int row = i >> 5;                 // bb*n + node (source row order)
        int bb  = (row >= n) ? 1 : 0;
        int node = row - bb * n;
        const float4* qs = (const float4*)(q + ((size_t)row << 8)) + (c << 1);
        const float4* ks = (const float4*)(k + ((size_t)row << 8)) + (c << 1);
        float4 a0 = qs[0], a1 = qs[1];
        float4 b0 = ks[0], b1 = ks[1];
        uint4 pa, pb;
        pa.x = (unsigned)f2bf(a0.x) | ((unsigned)f2bf(a0.y) << 16);
        pa.y = (unsigned)f2bf(a0.z) | ((unsigned)f2bf(a0.w) << 16);
        pa.z = (unsigned)f2bf(a1.x) | ((unsigned)f2bf(a1.y) << 16);
        pa.w = (unsigned)f2bf(a1.z) | ((unsigned)f2bf(a1.w) << 16);
        pb.x = (unsigned)f2bf(b0.x) | ((unsigned)f2bf(b0.y) << 16);
        pb.y = (unsigned)f2bf(b0.z) | ((unsigned)f2bf(b0.w) << 16);
        pb.z = (unsigned)f2bf(b1.x) | ((unsigned)f2bf(b1.y) << 16);
        pb.w = (unsigned)f2bf(b1.z) | ((unsigned)f2bf(b1.w) << 16);
        size_t dst = ((size_t)node * B + bb) * 32 + c;
        qc[dst] = pa;
        kc[dst] = pb;
    }
}

// K1: FUSED gather + scores + exp + segment atomicAdd.
// Softmax max-shift removed algebraically (|sc|<=~6, exp<=~400, safe).
// LATENCY FIX: EPW 4->8 and a hard sched_barrier(0) between the
// gather-issue loop and the compute loop. Round-0 build had
// VGPR_Count=32 -- compiler had sunk the gathers to their uses, leaving
// ~2 loads in flight per wave -> latency-bound at 47% HBM / 39% VALU.
// Now 16 dwordx4 gathers are issued back-to-back and stay outstanding
// (first use waits vmcnt(14)). Expect VGPR ~96-110, occupancy ~62%.
__global__ __launch_bounds__(256) void k_scores_fused(
    const ushort* __restrict__ qc, const ushort* __restrict__ kc,
    const int* __restrict__ e, const int* __restrict__ r,
    float* __restrict__ s, float* __restrict__ seg, int m)
{
    int wave = (int)((blockIdx.x * blockDim.x + threadIdx.x) >> 6);
    int lane = threadIdx.x & 63;
    int j0 = wave * EPW;
    if (j0 >= m) return;

    int rr[EPW];
    uint4 qa[EPW], kb[EPW];
    #pragma unroll
    for (int t = 0; t < EPW; ++t) {
        int j = j0 + t;
        int ok = (j < m);
        int e0 = ok ? e[j]     : 0;   // wave-uniform -> s_load
        int e1 = ok ? e[m + j] : 0;
        rr[t] = ok ? r[j]      : 0;
        qa[t] = ((const uint4*)(qc + (size_t)e0 * (B * D)))[lane];
        kb[t] = ((const uint4*)(kc + (size_t)e1 * (B * D)))[lane];
    }
    __builtin_amdgcn_sched_barrier(0);   // keep all 16 gathers in flight

    #pragma unroll
    for (int t = 0; t < EPW; ++t) {
        float p = 0.f;
        const unsigned* qw = (const unsigned*)&qa[t];
        const unsigned* kw = (const unsigned*)&kb[t];
        #pragma unroll
        for (int w = 0; w < 4; ++w) {
            float ql = __uint_as_float(qw[w] << 16);
            float qh = __uint_as_float(qw[w] & 0xFFFF0000u);
            float kl = __uint_as_float(kw[w] << 16);
            float kh = __uint_as_float(kw[w] & 0xFFFF0000u);
            p = fmaf(ql, kl, p);
            p = fmaf(qh, kh, p);
        }
        p += __shfl_xor(p, 1);
        p += __shfl_xor(p, 2);
        float ex = __expf(p * 0.0625f);     // /sqrt(256), no max shift
        if ((lane & 3) == 0 && (j0 + t) < m) {
            int bb = lane >> 5;
            int h  = (lane >> 2) & 7;
            s[((size_t)bb * m + (j0 + t)) * NH + h] = ex;
            atomicAdd(&seg[((size_t)rr[t] * B + bb) * NH + h], ex);
        }
    }
}

// fp32 fallback (ws too small for bf16 buffers): same fused structure.
__global__ __launch_bounds__(256) void k_scores_fused_f32(
    const float* __restrict__ q, const float* __restrict__ k,
    const int* __restrict__ e, const int* __restrict__ r,
    float* __restrict__ s, float* __restrict__ seg, int n, int m)
{
    int wave = (int)((blockIdx.x * blockDim.x + threadIdx.x) >> 6);
    int lane = threadIdx.x & 63;
    int j0 = wave * EPW32;
    if (j0 >= m) return;
    int e0[EPW32], e1[EPW32], rr[EPW32];
    #pragma unroll
    for (int t = 0; t < EPW32; ++t) {
        int j = j0 + t; int ok = (j < m);
        e0[t] = ok ? e[j] : 0; e1[t] = ok ? e[m + j] : 0; rr[t] = ok ? r[j] : 0;
    }
    float4 qa[B][EPW32], kb[B][EPW32];
    #pragma unroll
    for (int bb = 0; bb < B; ++bb)
        #pragma unroll
        for (int t = 0; t < EPW32; ++t) {
            qa[bb][t] = ((const float4*)(q + ((size_t)bb * n + e0[t]) * D))[lane];
            kb[bb][t] = ((const float4*)(k + ((size_t)bb * n + e1[t]) * D))[lane];
        }
    __builtin_amdgcn_sched_barrier(0);
    #pragma unroll
    for (int bb = 0; bb < B; ++bb)
        #pragma unroll
        for (int t = 0; t < EPW32; ++t) {
            float4 A = qa[bb][t], K4 = kb[bb][t];
            float p = A.x * K4.x + A.y * K4.y + A.z * K4.z + A.w * K4.w;
            p += __shfl_xor(p, 1); p += __shfl_xor(p, 2); p += __shfl_xor(p, 4);
            float ex = __expf(p * 0.0625f);
            if ((lane & 7) == 0 && (j0 + t) < m) {
                int h = lane >> 3;
                s[((size_t)bb * m + (j0 + t)) * NH + h] = ex;
                atomicAdd(&seg[((size_t)rr[t] * B + bb) * NH + h], ex);
            }
        }
}

// K2: one thread per (bb, edge). out = ex / (seg + eps), float4 in-place.
__global__ __launch_bounds__(256) void k_norm(
    float* __restrict__ s, const int* __restrict__ r,
    const float* __restrict__ seg, int m)
{
    int i = blockIdx.x * blockDim.x + threadIdx.x;
    int total = B * m;
    if (i >= total) return;
    int bb = (i >= m) ? 1 : 0;
    int j  = i - bb * m;
    const float4* sg = (const float4*)(seg + ((size_t)r[j] * B + bb) * NH);
    float4* sp = (float4*)(s + (size_t)i * NH);
    float4 d0 = sg[0], d1 = sg[1];
    float4 x0 = sp[0], x1 = sp[1];
    x0.x = __fdividef(x0.x, d0.x + 1e-16f);
    x0.y = __fdividef(x0.y, d0.y + 1e-16f);
    x0.z = __fdividef(x0.z, d0.z + 1e-16f);
    x0.w = __fdividef(x0.w, d0.w + 1e-16f);
    x1.x = __fdividef(x1.x, d1.x + 1e-16f);
    x1.y = __fdividef(x1.y, d1.y + 1e-16f);
    x1.z = __fdividef(x1.z, d1.z + 1e-16f);
    x1.w = __fdividef(x1.w, d1.w + 1e-16f);
    sp[0] = x0; sp[1] = x1;
}

extern "C" void kernel_launch(void* const* d_in, const int* in_sizes, int n_in,
                              void* d_out, int out_size, void* d_ws, size_t ws_size,
                              hipStream_t stream) {
    const float* q = (const float*)d_in[0];
    const float* k = (const float*)d_in[1];
    const int*   e = (const int*)d_in[2];
    const int*   r = (const int*)d_in[3];
    float* s = (float*)d_out;

    int n = in_sizes[0] / (B * D);          // 20000
    int m = in_sizes[3];                    // 320000

    // ws layout: seg(n*16 f32) | qc | kc
    size_t seg_bytes = (size_t)n * B * NH * sizeof(float);          // 1.28 MB
    size_t row_bytes = (size_t)n * B * D * sizeof(unsigned short);  // 20.48 MB
    float*  seg = (float*)d_ws;
    ushort* qc  = (ushort*)((char*)d_ws + seg_bytes);
    ushort* kc  = (ushort*)((char*)d_ws + seg_bytes + row_bytes);
    bool use_bf16 = ws_size >= (seg_bytes + 2 * row_bytes);

    hipMemsetAsync(d_ws, 0, seg_bytes, stream);

    int nblocks = (B * m + 255) / 256;

    if (use_bf16) {
        int cblocks = (n * B * 32 + 255) / 256;          // 5000
        int nwaves  = (m + EPW - 1) / EPW;               // 40000
        int sblocks = (nwaves + 3) / 4;                  // 10000
        k_conv<<<cblocks, 256, 0, stream>>>(q, k, (uint4*)qc, (uint4*)kc, n);
        k_scores_fused<<<sblocks, 256, 0, stream>>>(qc, kc, e, r, s, seg, m);
    } else {
        int nwaves  = (m + EPW32 - 1) / EPW32;
        int sblocks = (nwaves + 3) / 4;
        k_scores_fused_f32<<<sblocks, 256, 0, stream>>>(q, k, e, r, s, seg, n, m);
    }
    k_norm<<<nblocks, 256, 0, stream>>>(s, r, seg, m);
}